// Round 2
// baseline (340.279 us; speedup 1.0000x reference)
//
#include <hip/hip_runtime.h>

// GAT layer: N=100000 nodes, E=1600000 edges, 4 heads, D_in=128, D_out=32.
// Dtypes (settled): floats f32 (bf16-valued), edge_index int64 (flag-detected),
// output f32. GEMM = split-bf16 MFMA; scores fused via v = W^T a; Hw stored
// bf16. CSR build via 2-level bucket sort (LDS histograms + windowed scatter).
// Round-8: BISECT round. Round-7's 4-change bundle failed correctness; this is
// round-6 exactly, plus ONE change: k_aggr gather main loop deepened 4->8
// (same proven scalar pattern, guarded, no padding / no nontemporal / no
// fusion). Isolates the ILP-latency theory for the gather phase.

typedef __attribute__((ext_vector_type(8))) short short8_t;
typedef __attribute__((ext_vector_type(4))) float float4v;
typedef __attribute__((ext_vector_type(2))) float float2v;

static __device__ inline float bf2f(unsigned short u) {
    return __uint_as_float(((unsigned int)u) << 16);
}
static __device__ inline unsigned short f2bf(float f) {
    unsigned int u = __float_as_uint(f);
    return (unsigned short)((u + 0x7fffu + ((u >> 16) & 1u)) >> 16);
}
static __device__ inline void splitf(float v, unsigned short& h, unsigned short& l) {
    unsigned short hb = f2bf(v);
    h = hb;
    l = f2bf(v - bf2f(hb));  // residual exact in f32
}

// ---------------- K0: int-width detection (flags[1]: int64)
__global__ __launch_bounds__(256) void k_detect(const unsigned int* __restrict__ hwords,
                                                const unsigned int* __restrict__ ewords,
                                                int* __restrict__ flags) {
    __shared__ int s_bf, s_zero;
    if (threadIdx.x == 0) { s_bf = 0; s_zero = 0; }
    __syncthreads();
    int c = 0;
    for (int i = threadIdx.x; i < 1024; i += 256) {
        unsigned int e = (hwords[i] >> 7) & 0xFFu;
        c += (e >= 88 && e <= 140) ? 1 : 0;
    }
    atomicAdd(&s_bf, c);
    int z = 0;
    for (int i = threadIdx.x; i < 64; i += 256) z += (ewords[2 * i + 1] == 0u) ? 1 : 0;
    atomicAdd(&s_zero, z);
    __syncthreads();
    if (threadIdx.x == 0) {
        flags[0] = (s_bf >= 700) ? 1 : 0;
        flags[1] = (s_zero >= 32) ? 1 : 0;
    }
}

// ---------------- P1: per-block bucket histogram (bucket = tgt>>8), write tgt32.
// 16384 edges/block, 256 threads (64/thread). H[blk][b] row-major.
__global__ __launch_bounds__(256) void k_hist(const int* __restrict__ raw,
                                              const int* __restrict__ flags,
                                              int* __restrict__ tgt32, int* __restrict__ H,
                                              int E, int nmax, int NB) {
    __shared__ int h[512];
    for (int i = threadIdx.x; i < 512; i += 256) h[i] = 0;
    __syncthreads();
    bool i64 = flags[1] != 0;
    int base = blockIdx.x * 16384;
    for (int k = 0; k < 64; ++k) {
        int i = base + k * 256 + threadIdx.x;
        if (i < E) {
            int t = i64 ? raw[2 * ((size_t)E + i)] : raw[(size_t)E + i];
            t = t < 0 ? 0 : (t >= nmax ? nmax - 1 : t);
            tgt32[i] = t;
            atomicAdd(&h[t >> 8], 1);
        }
    }
    __syncthreads();
    for (int i = threadIdx.x; i < NB; i += 256) H[blockIdx.x * NB + i] = h[i];
}

// ---------------- bscan: H[blk][b] -> absolute write cursors; base[b]; offs[N]=E.
// One 1024-thread block; thread b owns bucket-column b (coalesced row access).
__global__ __launch_bounds__(1024) void k_bscan(int* __restrict__ H, int* __restrict__ base,
                                                int* __restrict__ offs, int nblkE, int NB,
                                                int N, int E) {
    __shared__ int wsum[16];
    int b = threadIdx.x;
    int run = 0;
    if (b < NB) {
        for (int blk = 0; blk < nblkE; ++blk) {
            int idx = blk * NB + b;
            int t = H[idx];
            H[idx] = run;
            run += t;
        }
    }
    // exclusive scan of run across 1024 threads
    int lane = threadIdx.x & 63, w = threadIdx.x >> 6;
    int inc = run;
    for (int d = 1; d < 64; d <<= 1) {
        int t = __shfl_up(inc, d, 64);
        if (lane >= d) inc += t;
    }
    if (lane == 63) wsum[w] = inc;
    __syncthreads();
    int wb = 0;
    for (int i = 0; i < w; ++i) wb += wsum[i];
    int e = wb + inc - run;
    if (b < NB) {
        base[b] = e;
        for (int blk = 0; blk < nblkE; ++blk) H[blk * NB + b] += e;
        if (b == NB - 1) {
            base[NB] = e + run;
            offs[N] = e + run;
        }
    }
}

// ---------------- P2: scatter (src,tgt) pairs grouped by bucket.
// LDS cursors seeded from Hoff -> per-(block,bucket) slots contiguous (~336B runs).
__global__ __launch_bounds__(256) void k_scat(const int* __restrict__ raw,
                                              const int* __restrict__ tgt32,
                                              const int* __restrict__ flags,
                                              const int* __restrict__ Hoff,
                                              uint2* __restrict__ pairs, int E, int nmax,
                                              int NB) {
    __shared__ int cnt[512];
    for (int i = threadIdx.x; i < NB; i += 256) cnt[i] = Hoff[blockIdx.x * NB + i];
    __syncthreads();
    bool i64 = flags[1] != 0;
    int base = blockIdx.x * 16384;
    for (int k = 0; k < 64; ++k) {
        int i = base + k * 256 + threadIdx.x;
        if (i < E) {
            int t = tgt32[i];
            int s = i64 ? raw[2 * (size_t)i] : raw[i];
            s = s < 0 ? 0 : (s >= nmax ? nmax - 1 : s);
            int slot = atomicAdd(&cnt[t >> 8], 1);
            uint2 p;
            p.x = (unsigned)s;
            p.y = (unsigned)t;
            pairs[slot] = p;
        }
    }
}

// ---------------- 256-thread block exclusive scan helper
__device__ inline int block_excl_scan(int v) {
    __shared__ int wsum[8];
    int lane = threadIdx.x & 63, w = threadIdx.x >> 6;
    int inc = v;
    for (int d = 1; d < 64; d <<= 1) {
        int t = __shfl_up(inc, d, 64);
        if (lane >= d) inc += t;
    }
    if (lane == 63) wsum[w] = inc;
    __syncthreads();
    int base = 0;
    for (int i = 0; i < w; ++i) base += wsum[i];
    __syncthreads();
    return base + inc - v;
}

// ---------------- P3: per-bucket local CSR build. One block per 256-node window.
// All csr writes land in the bucket's ~16KB window from one block -> L2 merges.
__global__ __launch_bounds__(256) void k_local(const uint2* __restrict__ pairs,
                                               const int* __restrict__ base,
                                               int* __restrict__ offs, int* __restrict__ csr,
                                               int N, int NB) {
    __shared__ int dcnt[256];
    __shared__ int cur[256];
    int b = blockIdx.x;
    int lo = base[b], hi = base[b + 1];
    int nodeBase = b << 8;
    dcnt[threadIdx.x] = 0;
    __syncthreads();
    for (int i = lo + threadIdx.x; i < hi; i += 256) atomicAdd(&dcnt[pairs[i].y & 255], 1);
    __syncthreads();
    int v = dcnt[threadIdx.x];
    int e = block_excl_scan(v);
    int n = nodeBase + threadIdx.x;
    if (n < N) offs[n] = lo + e;
    cur[threadIdx.x] = lo + e;
    __syncthreads();
    for (int i = lo + threadIdx.x; i < hi; i += 256) {
        uint2 p = pairs[i];
        int slot = atomicAdd(&cur[p.y & 255], 1);
        csr[slot] = (int)p.x;
    }
}

// ---------------- K0c: v_src[h][k] = sum_o W[h][o][k]*A_src[h][o] (and v_tgt)
__global__ __launch_bounds__(256) void k_prep(const float* __restrict__ Wf,
                                              const float* __restrict__ Asrc,
                                              const float* __restrict__ Atgt,
                                              float* __restrict__ vsrc,
                                              float* __restrict__ vtgt) {
    __shared__ float As[128], At[128];
    if (threadIdx.x < 128) {
        As[threadIdx.x] = Asrc[threadIdx.x];
        At[threadIdx.x] = Atgt[threadIdx.x];
    }
    __syncthreads();
    for (int p = threadIdx.x; p < 512; p += 256) {
        int h = p >> 7, k = p & 127;
        float a = 0.f, b = 0.f;
        for (int o = 0; o < 32; ++o) {
            float w = Wf[((size_t)(h * 32 + o)) * 128 + k];
            a += w * As[h * 32 + o];
            b += w * At[h * 32 + o];
        }
        vsrc[p] = a;  // p == h*128+k
        vtgt[p] = b;
    }
}

// ---------------- K1: fused GEMM + scores (split-bf16 MFMA). See round-4 notes.
__global__ __launch_bounds__(256) void k_hw(const float* __restrict__ Hf,
                                            const float* __restrict__ Wf,
                                            const float* __restrict__ vsrc,
                                            const float* __restrict__ vtgt,
                                            unsigned short* __restrict__ Hwb,
                                            float* __restrict__ s_src,
                                            float* __restrict__ s_tgt, int nnodes) {
    __shared__ __align__(16) unsigned short Wh[64 * 136];
    __shared__ __align__(16) unsigned short Wl[64 * 136];
    __shared__ __align__(16) unsigned short Sh[16 * 136];
    __shared__ __align__(16) unsigned short Sl[16 * 136];

    int wave = threadIdx.x >> 6;
    int lane = threadIdx.x & 63;
    int mrow = lane & 15;
    int quad = lane >> 4;

    for (int i = threadIdx.x; i < 512; i += 256) {
        int r = i >> 5, c4 = (i & 31) * 4;
        float4v v = {0.f, 0.f, 0.f, 0.f};
        if (r < 4) v = *(const float4v*)(vsrc + r * 128 + c4);
        else if (r < 8) v = *(const float4v*)(vtgt + (r - 4) * 128 + c4);
        ushort4 h4, l4;
        unsigned short hh, ll;
        splitf(v[0], hh, ll); h4.x = hh; l4.x = ll;
        splitf(v[1], hh, ll); h4.y = hh; l4.y = ll;
        splitf(v[2], hh, ll); h4.z = hh; l4.z = ll;
        splitf(v[3], hh, ll); h4.w = hh; l4.w = ll;
        *(ushort4*)&Sh[r * 136 + c4] = h4;
        *(ushort4*)&Sl[r * 136 + c4] = l4;
    }

    const float4v* wsrc = (const float4v*)Wf;

    for (int hb = 0; hb < 2; ++hb) {
        if (hb) __syncthreads();
        for (int i = threadIdx.x; i < 2048; i += 256) {
            int r = i >> 5, c4 = (i & 31) * 4;
            float4v v = wsrc[(hb * 64 + r) * 32 + (i & 31)];
            ushort4 h4, l4;
            unsigned short hh, ll;
            splitf(v[0], hh, ll); h4.x = hh; l4.x = ll;
            splitf(v[1], hh, ll); h4.y = hh; l4.y = ll;
            splitf(v[2], hh, ll); h4.z = hh; l4.z = ll;
            splitf(v[3], hh, ll); h4.w = hh; l4.w = ll;
            *(ushort4*)&Wh[r * 136 + c4] = h4;
            *(ushort4*)&Wl[r * 136 + c4] = l4;
        }
        __syncthreads();

        for (int nh = 0; nh < 2; ++nh) {
            int nbase = blockIdx.x * 128 + (wave * 2 + nh) * 16;
            if (nbase >= nnodes) continue;
            int anode = nbase + mrow;
            int nclamp = anode < nnodes ? anode : nnodes - 1;
            const float* Hp = Hf + (size_t)nclamp * 128 + quad * 8;

            float4v acc[4] = {};
            float4v accS = {};
            for (int kc = 0; kc < 4; ++kc) {
                float4v va = *(const float4v*)(Hp + kc * 32);
                float4v vb = *(const float4v*)(Hp + kc * 32 + 4);
                short8_t ah, al;
                unsigned short hh, ll;
                splitf(va[0], hh, ll); ah[0] = (short)hh; al[0] = (short)ll;
                splitf(va[1], hh, ll); ah[1] = (short)hh; al[1] = (short)ll;
                splitf(va[2], hh, ll); ah[2] = (short)hh; al[2] = (short)ll;
                splitf(va[3], hh, ll); ah[3] = (short)hh; al[3] = (short)ll;
                splitf(vb[0], hh, ll); ah[4] = (short)hh; al[4] = (short)ll;
                splitf(vb[1], hh, ll); ah[5] = (short)hh; al[5] = (short)ll;
                splitf(vb[2], hh, ll); ah[6] = (short)hh; al[6] = (short)ll;
                splitf(vb[3], hh, ll); ah[7] = (short)hh; al[7] = (short)ll;
                for (int t = 0; t < 4; ++t) {
                    int boff = (t * 16 + mrow) * 136 + kc * 32 + quad * 8;
                    short8_t bh = *(const short8_t*)&Wh[boff];
                    short8_t bl = *(const short8_t*)&Wl[boff];
                    acc[t] = __builtin_amdgcn_mfma_f32_16x16x32_bf16(ah, bh, acc[t], 0, 0, 0);
                    acc[t] = __builtin_amdgcn_mfma_f32_16x16x32_bf16(al, bh, acc[t], 0, 0, 0);
                    acc[t] = __builtin_amdgcn_mfma_f32_16x16x32_bf16(ah, bl, acc[t], 0, 0, 0);
                }
                if (hb == 0) {
                    int soff = mrow * 136 + kc * 32 + quad * 8;
                    short8_t bh = *(const short8_t*)&Sh[soff];
                    short8_t bl = *(const short8_t*)&Sl[soff];
                    accS = __builtin_amdgcn_mfma_f32_16x16x32_bf16(ah, bh, accS, 0, 0, 0);
                    accS = __builtin_amdgcn_mfma_f32_16x16x32_bf16(al, bh, accS, 0, 0, 0);
                    accS = __builtin_amdgcn_mfma_f32_16x16x32_bf16(ah, bl, accS, 0, 0, 0);
                }
            }
            for (int t = 0; t < 4; ++t)
                for (int r = 0; r < 4; ++r) {
                    int nrow = nbase + quad * 4 + r;
                    if (nrow < nnodes)
                        Hwb[(size_t)nrow * 128 + hb * 64 + t * 16 + mrow] = f2bf(acc[t][r]);
                }
            if (hb == 0) {
                for (int r = 0; r < 4; ++r) {
                    int nrow = nbase + quad * 4 + r;
                    if (nrow < nnodes) {
                        if (mrow < 4) s_src[nrow * 4 + mrow] = accS[r];
                        else if (mrow < 8) s_tgt[nrow * 4 + (mrow - 4)] = accS[r];
                    }
                }
            }
        }
    }
}

// ---------------- K5: per-node softmax + aggregation + ELU.
// Round-8: main gather loop deepened 4 -> 8 (guarded, same scalar pattern;
// 8 outstanding 256B row loads per wave instead of 4). 4-wide + scalar tails
// unchanged from round-6.
__global__ __launch_bounds__(256) void k_aggr(const int* __restrict__ offs,
                                              const int* __restrict__ csr,
                                              const float* __restrict__ s_src,
                                              const float* __restrict__ s_tgt,
                                              const unsigned int* __restrict__ Hwb,
                                              float* __restrict__ out, int nnodes) {
    __shared__ int srcs[4][64];
    __shared__ __align__(16) float wbuf[4][64 * 4];
    int wave = threadIdx.x >> 6, lane = threadIdx.x & 63;
    int n = blockIdx.x * 4 + wave;
    if (n >= nnodes) return;
    int off = offs[n];
    int deg = offs[n + 1] - off;
    int h = lane >> 4;

    const float4v* ss4 = (const float4v*)s_src;
    float4v st = ((const float4v*)s_tgt)[n];

    float se0 = 0.f, se1 = 0.f, se2 = 0.f, se3 = 0.f;
    float acc0 = 0.f, acc1 = 0.f;

    for (int base = 0; base < deg; base += 64) {
        int cnt = min(64, deg - base);
        asm volatile("s_waitcnt lgkmcnt(0)" ::: "memory");
        if (lane < cnt) {
            int s = csr[off + base + lane];
            srcs[wave][lane] = s;
            float4v ss = ss4[s];
            float4v w;
            for (int c = 0; c < 4; ++c) {
                float x = ss[c] + st[c];
                x = fminf(fmaxf(x, 0.2f * x), 60.f);
                w[c] = __expf(x);
            }
            se0 += w[0]; se1 += w[1]; se2 += w[2]; se3 += w[3];
            *(float4v*)&wbuf[wave][lane * 4] = w;
        }
        asm volatile("s_waitcnt lgkmcnt(0)" ::: "memory");

        int k = 0;
        for (; k + 8 <= cnt; k += 8) {
            int q0 = srcs[wave][k], q1 = srcs[wave][k + 1];
            int q2 = srcs[wave][k + 2], q3 = srcs[wave][k + 3];
            int q4 = srcs[wave][k + 4], q5 = srcs[wave][k + 5];
            int q6 = srcs[wave][k + 6], q7 = srcs[wave][k + 7];
            float w0 = wbuf[wave][k * 4 + h], w1 = wbuf[wave][(k + 1) * 4 + h];
            float w2 = wbuf[wave][(k + 2) * 4 + h], w3 = wbuf[wave][(k + 3) * 4 + h];
            float w4 = wbuf[wave][(k + 4) * 4 + h], w5 = wbuf[wave][(k + 5) * 4 + h];
            float w6 = wbuf[wave][(k + 6) * 4 + h], w7 = wbuf[wave][(k + 7) * 4 + h];
            unsigned int u0 = Hwb[(size_t)q0 * 64 + lane];
            unsigned int u1 = Hwb[(size_t)q1 * 64 + lane];
            unsigned int u2 = Hwb[(size_t)q2 * 64 + lane];
            unsigned int u3 = Hwb[(size_t)q3 * 64 + lane];
            unsigned int u4 = Hwb[(size_t)q4 * 64 + lane];
            unsigned int u5 = Hwb[(size_t)q5 * 64 + lane];
            unsigned int u6 = Hwb[(size_t)q6 * 64 + lane];
            unsigned int u7 = Hwb[(size_t)q7 * 64 + lane];
            acc0 += w0 * __uint_as_float(u0 << 16);
            acc1 += w0 * __uint_as_float(u0 & 0xffff0000u);
            acc0 += w1 * __uint_as_float(u1 << 16);
            acc1 += w1 * __uint_as_float(u1 & 0xffff0000u);
            acc0 += w2 * __uint_as_float(u2 << 16);
            acc1 += w2 * __uint_as_float(u2 & 0xffff0000u);
            acc0 += w3 * __uint_as_float(u3 << 16);
            acc1 += w3 * __uint_as_float(u3 & 0xffff0000u);
            acc0 += w4 * __uint_as_float(u4 << 16);
            acc1 += w4 * __uint_as_float(u4 & 0xffff0000u);
            acc0 += w5 * __uint_as_float(u5 << 16);
            acc1 += w5 * __uint_as_float(u5 & 0xffff0000u);
            acc0 += w6 * __uint_as_float(u6 << 16);
            acc1 += w6 * __uint_as_float(u6 & 0xffff0000u);
            acc0 += w7 * __uint_as_float(u7 << 16);
            acc1 += w7 * __uint_as_float(u7 & 0xffff0000u);
        }
        for (; k + 4 <= cnt; k += 4) {
            int q0 = srcs[wave][k], q1 = srcs[wave][k + 1];
            int q2 = srcs[wave][k + 2], q3 = srcs[wave][k + 3];
            float w0 = wbuf[wave][k * 4 + h], w1 = wbuf[wave][(k + 1) * 4 + h];
            float w2 = wbuf[wave][(k + 2) * 4 + h], w3 = wbuf[wave][(k + 3) * 4 + h];
            unsigned int u0 = Hwb[(size_t)q0 * 64 + lane];
            unsigned int u1 = Hwb[(size_t)q1 * 64 + lane];
            unsigned int u2 = Hwb[(size_t)q2 * 64 + lane];
            unsigned int u3 = Hwb[(size_t)q3 * 64 + lane];
            acc0 += w0 * __uint_as_float(u0 << 16);
            acc1 += w0 * __uint_as_float(u0 & 0xffff0000u);
            acc0 += w1 * __uint_as_float(u1 << 16);
            acc1 += w1 * __uint_as_float(u1 & 0xffff0000u);
            acc0 += w2 * __uint_as_float(u2 << 16);
            acc1 += w2 * __uint_as_float(u2 & 0xffff0000u);
            acc0 += w3 * __uint_as_float(u3 << 16);
            acc1 += w3 * __uint_as_float(u3 & 0xffff0000u);
        }
        for (; k < cnt; ++k) {
            int q = srcs[wave][k];
            float w = wbuf[wave][k * 4 + h];
            unsigned int u = Hwb[(size_t)q * 64 + lane];
            acc0 += w * __uint_as_float(u << 16);
            acc1 += w * __uint_as_float(u & 0xffff0000u);
        }
    }

    for (int d = 1; d < 64; d <<= 1) {
        se0 += __shfl_xor(se0, d, 64);
        se1 += __shfl_xor(se1, d, 64);
        se2 += __shfl_xor(se2, d, 64);
        se3 += __shfl_xor(se3, d, 64);
    }
    float seh = (h == 0) ? se0 : (h == 1) ? se1 : (h == 2) ? se2 : se3;
    float inv = seh > 0.f ? 1.0f / seh : 0.f;
    acc0 *= inv;
    acc1 *= inv;
    acc0 = acc0 > 0.f ? acc0 : __expf(acc0) - 1.0f;
    acc1 = acc1 > 0.f ? acc1 : __expf(acc1) - 1.0f;

    int o = (2 * lane) & 31;
    float2v val = {acc0, acc1};
    *(float2v*)&out[(((size_t)h * nnodes + n) * 32) + o] = val;
}

extern "C" void kernel_launch(void* const* d_in, const int* in_sizes, int n_in,
                              void* d_out, int out_size, void* d_ws, size_t ws_size,
                              hipStream_t stream) {
    const float* Hin = (const float*)d_in[0];
    const int* ei_raw = (const int*)d_in[1];
    const float* W = (const float*)d_in[2];
    const float* Asrc = (const float*)d_in[3];
    const float* Atgt = (const float*)d_in[4];
    int N = in_sizes[0] / 128;
    int E = in_sizes[1] / 2;
    int NB = (N + 255) >> 8;        // node buckets (256 nodes each)
    int nblkE = (E + 16383) >> 14;  // edge blocks (16384 edges each)

    char* ws = (char*)d_ws;
    size_t p = 0;
    auto alloc = [&](size_t bytes) {
        void* r = ws + p;
        p = (p + bytes + 511) & ~(size_t)511;
        return r;
    };
    unsigned short* Hwb = (unsigned short*)alloc((size_t)N * 128 * 2);  // 25.6 MB
    float* s_src = (float*)alloc((size_t)N * 4 * 4);
    float* s_tgt = (float*)alloc((size_t)N * 4 * 4);
    int* offs = (int*)alloc((size_t)(N + 1) * 4);
    int* csr = (int*)alloc((size_t)E * 4);
    int* tgt32 = (int*)alloc((size_t)E * 4);
    uint2* pairs = (uint2*)alloc((size_t)E * 8);
    int* H = (int*)alloc((size_t)nblkE * NB * 4);
    int* base = (int*)alloc((size_t)(NB + 1) * 4);
    float* vsrc = (float*)alloc(512 * 4);
    float* vtgt = (float*)alloc(512 * 4);
    int* flags = (int*)alloc(2 * 4);

    k_detect<<<dim3(1), 256, 0, stream>>>((const unsigned int*)Hin,
                                          (const unsigned int*)ei_raw, flags);
    k_hist<<<dim3(nblkE), 256, 0, stream>>>(ei_raw, flags, tgt32, H, E, N, NB);
    k_bscan<<<dim3(1), 1024, 0, stream>>>(H, base, offs, nblkE, NB, N, E);
    k_scat<<<dim3(nblkE), 256, 0, stream>>>(ei_raw, tgt32, flags, H, pairs, E, N, NB);
    k_local<<<dim3(NB), 256, 0, stream>>>(pairs, base, offs, csr, N, NB);

    k_prep<<<dim3(1), 256, 0, stream>>>(W, Asrc, Atgt, vsrc, vtgt);
    k_hw<<<dim3((N + 127) / 128), 256, 0, stream>>>(Hin, W, vsrc, vtgt, Hwb, s_src, s_tgt, N);

    k_aggr<<<dim3((N + 3) / 4), 256, 0, stream>>>(offs, csr, s_src, s_tgt,
                                                  (const unsigned int*)Hwb, (float*)d_out, N);
}

// Round 3
// 328.381 us; speedup vs baseline: 1.0362x; 1.0362x over previous
//
#include <hip/hip_runtime.h>

// GAT layer: N=100000 nodes, E=1600000 edges, 4 heads, D_in=128, D_out=32.
// Dtypes (settled): floats f32 (bf16-valued), edge_index int64 (flag-detected),
// output f32. Hw stored bf16. CSR build via 2-level bucket sort.
// Round-9 changes (k_aggr untouched = round-8 passing version, 76us):
//  - k_hw: inputs are bf16-valued f32 => split-lo parts are exactly zero.
//    Dropped Wl staging + al computation + 2 of 3 MFMAs per product
//    (bitwise-identical under the hypothesis; prediction absmax==0.03125).
//    S path keeps hi+lo (S = W^T a computed in f32, genuinely full-precision).
//  - k_prep fused into k_hw (per-block recompute, same f32 math, one fewer
//    single-block bubble). k_detect removed; int64 detection folded into
//    k_hist/k_scat as a per-block wave-0 ballot (flags[0] was never consumed).
//  - NOT re-landed from failed round-7: padded-16 gather, nontemporal csr
//    load (prime suspect: nt read of L2-dirty producer data).

typedef __attribute__((ext_vector_type(8))) short short8_t;
typedef __attribute__((ext_vector_type(4))) float float4v;
typedef __attribute__((ext_vector_type(2))) float float2v;

static __device__ inline float bf2f(unsigned short u) {
    return __uint_as_float(((unsigned int)u) << 16);
}
static __device__ inline unsigned short f2bf(float f) {
    unsigned int u = __float_as_uint(f);
    return (unsigned short)((u + 0x7fffu + ((u >> 16) & 1u)) >> 16);
}
static __device__ inline void splitf(float v, unsigned short& h, unsigned short& l) {
    unsigned short hb = f2bf(v);
    h = hb;
    l = f2bf(v - bf2f(hb));  // residual exact in f32
}

// ---------------- P1: per-block bucket histogram (bucket = tgt>>8), write tgt32.
// 16384 edges/block, 256 threads (64/thread). H[blk][b] row-major.
// int64 detection inlined: wave 0 ballots zeros among first 64 high dwords
// (deterministic, identical result in every block).
__global__ __launch_bounds__(256) void k_hist(const int* __restrict__ raw,
                                              int* __restrict__ tgt32, int* __restrict__ H,
                                              int E, int nmax, int NB) {
    __shared__ int h[512];
    __shared__ int s_i64;
    for (int i = threadIdx.x; i < 512; i += 256) h[i] = 0;
    if (threadIdx.x < 64) {
        unsigned int hiw = ((const unsigned int*)raw)[2 * threadIdx.x + 1];
        unsigned long long b = __ballot(hiw == 0u);
        if (threadIdx.x == 0) s_i64 = (__popcll(b) >= 32) ? 1 : 0;
    }
    __syncthreads();
    bool i64 = s_i64 != 0;
    int base = blockIdx.x * 16384;
    for (int k = 0; k < 64; ++k) {
        int i = base + k * 256 + threadIdx.x;
        if (i < E) {
            int t = i64 ? raw[2 * ((size_t)E + i)] : raw[(size_t)E + i];
            t = t < 0 ? 0 : (t >= nmax ? nmax - 1 : t);
            tgt32[i] = t;
            atomicAdd(&h[t >> 8], 1);
        }
    }
    __syncthreads();
    for (int i = threadIdx.x; i < NB; i += 256) H[blockIdx.x * NB + i] = h[i];
}

// ---------------- bscan: H[blk][b] -> absolute write cursors; base[b]; offs[N]=E.
__global__ __launch_bounds__(1024) void k_bscan(int* __restrict__ H, int* __restrict__ base,
                                                int* __restrict__ offs, int nblkE, int NB,
                                                int N, int E) {
    __shared__ int wsum[16];
    int b = threadIdx.x;
    int run = 0;
    if (b < NB) {
        for (int blk = 0; blk < nblkE; ++blk) {
            int idx = blk * NB + b;
            int t = H[idx];
            H[idx] = run;
            run += t;
        }
    }
    int lane = threadIdx.x & 63, w = threadIdx.x >> 6;
    int inc = run;
    for (int d = 1; d < 64; d <<= 1) {
        int t = __shfl_up(inc, d, 64);
        if (lane >= d) inc += t;
    }
    if (lane == 63) wsum[w] = inc;
    __syncthreads();
    int wb = 0;
    for (int i = 0; i < w; ++i) wb += wsum[i];
    int e = wb + inc - run;
    if (b < NB) {
        base[b] = e;
        for (int blk = 0; blk < nblkE; ++blk) H[blk * NB + b] += e;
        if (b == NB - 1) {
            base[NB] = e + run;
            offs[N] = e + run;
        }
    }
}

// ---------------- P2: scatter (src,tgt) pairs grouped by bucket.
__global__ __launch_bounds__(256) void k_scat(const int* __restrict__ raw,
                                              const int* __restrict__ tgt32,
                                              const int* __restrict__ Hoff,
                                              uint2* __restrict__ pairs, int E, int nmax,
                                              int NB) {
    __shared__ int cnt[512];
    __shared__ int s_i64;
    for (int i = threadIdx.x; i < NB; i += 256) cnt[i] = Hoff[blockIdx.x * NB + i];
    if (threadIdx.x < 64) {
        unsigned int hiw = ((const unsigned int*)raw)[2 * threadIdx.x + 1];
        unsigned long long b = __ballot(hiw == 0u);
        if (threadIdx.x == 0) s_i64 = (__popcll(b) >= 32) ? 1 : 0;
    }
    __syncthreads();
    bool i64 = s_i64 != 0;
    int base = blockIdx.x * 16384;
    for (int k = 0; k < 64; ++k) {
        int i = base + k * 256 + threadIdx.x;
        if (i < E) {
            int t = tgt32[i];
            int s = i64 ? raw[2 * (size_t)i] : raw[i];
            s = s < 0 ? 0 : (s >= nmax ? nmax - 1 : s);
            int slot = atomicAdd(&cnt[t >> 8], 1);
            uint2 p;
            p.x = (unsigned)s;
            p.y = (unsigned)t;
            pairs[slot] = p;
        }
    }
}

// ---------------- 256-thread block exclusive scan helper
__device__ inline int block_excl_scan(int v) {
    __shared__ int wsum[8];
    int lane = threadIdx.x & 63, w = threadIdx.x >> 6;
    int inc = v;
    for (int d = 1; d < 64; d <<= 1) {
        int t = __shfl_up(inc, d, 64);
        if (lane >= d) inc += t;
    }
    if (lane == 63) wsum[w] = inc;
    __syncthreads();
    int base = 0;
    for (int i = 0; i < w; ++i) base += wsum[i];
    __syncthreads();
    return base + inc - v;
}

// ---------------- P3: per-bucket local CSR build. One block per 256-node window.
__global__ __launch_bounds__(256) void k_local(const uint2* __restrict__ pairs,
                                               const int* __restrict__ base,
                                               int* __restrict__ offs, int* __restrict__ csr,
                                               int N, int NB) {
    __shared__ int dcnt[256];
    __shared__ int cur[256];
    int b = blockIdx.x;
    int lo = base[b], hi = base[b + 1];
    int nodeBase = b << 8;
    dcnt[threadIdx.x] = 0;
    __syncthreads();
    for (int i = lo + threadIdx.x; i < hi; i += 256) atomicAdd(&dcnt[pairs[i].y & 255], 1);
    __syncthreads();
    int v = dcnt[threadIdx.x];
    int e = block_excl_scan(v);
    int n = nodeBase + threadIdx.x;
    if (n < N) offs[n] = lo + e;
    cur[threadIdx.x] = lo + e;
    __syncthreads();
    for (int i = lo + threadIdx.x; i < hi; i += 256) {
        uint2 p = pairs[i];
        int slot = atomicAdd(&cur[p.y & 255], 1);
        csr[slot] = (int)p.x;
    }
}

// ---------------- K1: fused GEMM + scores. bf16-valued inputs => single hi-part
// MFMA for the main GEMM (lo parts are exactly zero); S path (v = W^T a in f32)
// keeps hi+lo. v recomputed per block from f32 W (was k_prep).
__global__ __launch_bounds__(256) void k_hw(const float* __restrict__ Hf,
                                            const float* __restrict__ Wf,
                                            const float* __restrict__ Asrc,
                                            const float* __restrict__ Atgt,
                                            unsigned short* __restrict__ Hwb,
                                            float* __restrict__ s_src,
                                            float* __restrict__ s_tgt, int nnodes) {
    __shared__ __align__(16) unsigned short Wh[64 * 136];
    __shared__ __align__(16) unsigned short Sh[16 * 136];
    __shared__ __align__(16) unsigned short Sl[16 * 136];
    __shared__ float sAs[128], sAt[128];

    int wave = threadIdx.x >> 6;
    int lane = threadIdx.x & 63;
    int mrow = lane & 15;
    int quad = lane >> 4;

    if (threadIdx.x < 128) {
        sAs[threadIdx.x] = Asrc[threadIdx.x];
        sAt[threadIdx.x] = Atgt[threadIdx.x];
    }
    __syncthreads();

    // S rows: r in [0,4) = v_src head r, [4,8) = v_tgt head r-4, [8,16) = 0.
    // v[h][k] = sum_o W[h][o][k] * A[h][o] in f32 (identical math to k_prep).
    for (int i = threadIdx.x; i < 512; i += 256) {
        int r = i >> 5, c4 = (i & 31) * 4;
        float4v v = {0.f, 0.f, 0.f, 0.f};
        if (r < 8) {
            int hh_ = r & 3;
            const float* Ap = (r < 4) ? sAs : sAt;
            for (int o = 0; o < 32; ++o) {
                float4v w4 = *(const float4v*)(Wf + ((size_t)(hh_ * 32 + o)) * 128 + c4);
                float a = Ap[hh_ * 32 + o];
                v[0] += w4[0] * a;
                v[1] += w4[1] * a;
                v[2] += w4[2] * a;
                v[3] += w4[3] * a;
            }
        }
        ushort4 h4, l4;
        unsigned short hh, ll;
        splitf(v[0], hh, ll); h4.x = hh; l4.x = ll;
        splitf(v[1], hh, ll); h4.y = hh; l4.y = ll;
        splitf(v[2], hh, ll); h4.z = hh; l4.z = ll;
        splitf(v[3], hh, ll); h4.w = hh; l4.w = ll;
        *(ushort4*)&Sh[r * 136 + c4] = h4;
        *(ushort4*)&Sl[r * 136 + c4] = l4;
    }

    const float4v* wsrc = (const float4v*)Wf;

    for (int hb = 0; hb < 2; ++hb) {
        if (hb) __syncthreads();
        for (int i = threadIdx.x; i < 2048; i += 256) {
            int r = i >> 5, c4 = (i & 31) * 4;
            float4v v = wsrc[(hb * 64 + r) * 32 + (i & 31)];
            ushort4 h4;
            h4.x = f2bf(v[0]);
            h4.y = f2bf(v[1]);
            h4.z = f2bf(v[2]);
            h4.w = f2bf(v[3]);
            *(ushort4*)&Wh[r * 136 + c4] = h4;
        }
        __syncthreads();

        for (int nh = 0; nh < 2; ++nh) {
            int nbase = blockIdx.x * 128 + (wave * 2 + nh) * 16;
            if (nbase >= nnodes) continue;
            int anode = nbase + mrow;
            int nclamp = anode < nnodes ? anode : nnodes - 1;
            const float* Hp = Hf + (size_t)nclamp * 128 + quad * 8;

            float4v acc[4] = {};
            float4v accS = {};
            for (int kc = 0; kc < 4; ++kc) {
                float4v va = *(const float4v*)(Hp + kc * 32);
                float4v vb = *(const float4v*)(Hp + kc * 32 + 4);
                short8_t ah;
                ah[0] = (short)f2bf(va[0]);
                ah[1] = (short)f2bf(va[1]);
                ah[2] = (short)f2bf(va[2]);
                ah[3] = (short)f2bf(va[3]);
                ah[4] = (short)f2bf(vb[0]);
                ah[5] = (short)f2bf(vb[1]);
                ah[6] = (short)f2bf(vb[2]);
                ah[7] = (short)f2bf(vb[3]);
                for (int t = 0; t < 4; ++t) {
                    int boff = (t * 16 + mrow) * 136 + kc * 32 + quad * 8;
                    short8_t bh = *(const short8_t*)&Wh[boff];
                    acc[t] = __builtin_amdgcn_mfma_f32_16x16x32_bf16(ah, bh, acc[t], 0, 0, 0);
                }
                if (hb == 0) {
                    int soff = mrow * 136 + kc * 32 + quad * 8;
                    short8_t sh = *(const short8_t*)&Sh[soff];
                    short8_t sl = *(const short8_t*)&Sl[soff];
                    accS = __builtin_amdgcn_mfma_f32_16x16x32_bf16(ah, sh, accS, 0, 0, 0);
                    accS = __builtin_amdgcn_mfma_f32_16x16x32_bf16(ah, sl, accS, 0, 0, 0);
                }
            }
            for (int t = 0; t < 4; ++t)
                for (int r = 0; r < 4; ++r) {
                    int nrow = nbase + quad * 4 + r;
                    if (nrow < nnodes)
                        Hwb[(size_t)nrow * 128 + hb * 64 + t * 16 + mrow] = f2bf(acc[t][r]);
                }
            if (hb == 0) {
                for (int r = 0; r < 4; ++r) {
                    int nrow = nbase + quad * 4 + r;
                    if (nrow < nnodes) {
                        if (mrow < 4) s_src[nrow * 4 + mrow] = accS[r];
                        else if (mrow < 8) s_tgt[nrow * 4 + (mrow - 4)] = accS[r];
                    }
                }
            }
        }
    }
}

// ---------------- K5: per-node softmax + aggregation + ELU (round-8 version,
// untouched: 8-deep + 4-deep + scalar gather tails).
__global__ __launch_bounds__(256) void k_aggr(const int* __restrict__ offs,
                                              const int* __restrict__ csr,
                                              const float* __restrict__ s_src,
                                              const float* __restrict__ s_tgt,
                                              const unsigned int* __restrict__ Hwb,
                                              float* __restrict__ out, int nnodes) {
    __shared__ int srcs[4][64];
    __shared__ __align__(16) float wbuf[4][64 * 4];
    int wave = threadIdx.x >> 6, lane = threadIdx.x & 63;
    int n = blockIdx.x * 4 + wave;
    if (n >= nnodes) return;
    int off = offs[n];
    int deg = offs[n + 1] - off;
    int h = lane >> 4;

    const float4v* ss4 = (const float4v*)s_src;
    float4v st = ((const float4v*)s_tgt)[n];

    float se0 = 0.f, se1 = 0.f, se2 = 0.f, se3 = 0.f;
    float acc0 = 0.f, acc1 = 0.f;

    for (int base = 0; base < deg; base += 64) {
        int cnt = min(64, deg - base);
        asm volatile("s_waitcnt lgkmcnt(0)" ::: "memory");
        if (lane < cnt) {
            int s = csr[off + base + lane];
            srcs[wave][lane] = s;
            float4v ss = ss4[s];
            float4v w;
            for (int c = 0; c < 4; ++c) {
                float x = ss[c] + st[c];
                x = fminf(fmaxf(x, 0.2f * x), 60.f);
                w[c] = __expf(x);
            }
            se0 += w[0]; se1 += w[1]; se2 += w[2]; se3 += w[3];
            *(float4v*)&wbuf[wave][lane * 4] = w;
        }
        asm volatile("s_waitcnt lgkmcnt(0)" ::: "memory");

        int k = 0;
        for (; k + 8 <= cnt; k += 8) {
            int q0 = srcs[wave][k], q1 = srcs[wave][k + 1];
            int q2 = srcs[wave][k + 2], q3 = srcs[wave][k + 3];
            int q4 = srcs[wave][k + 4], q5 = srcs[wave][k + 5];
            int q6 = srcs[wave][k + 6], q7 = srcs[wave][k + 7];
            float w0 = wbuf[wave][k * 4 + h], w1 = wbuf[wave][(k + 1) * 4 + h];
            float w2 = wbuf[wave][(k + 2) * 4 + h], w3 = wbuf[wave][(k + 3) * 4 + h];
            float w4 = wbuf[wave][(k + 4) * 4 + h], w5 = wbuf[wave][(k + 5) * 4 + h];
            float w6 = wbuf[wave][(k + 6) * 4 + h], w7 = wbuf[wave][(k + 7) * 4 + h];
            unsigned int u0 = Hwb[(size_t)q0 * 64 + lane];
            unsigned int u1 = Hwb[(size_t)q1 * 64 + lane];
            unsigned int u2 = Hwb[(size_t)q2 * 64 + lane];
            unsigned int u3 = Hwb[(size_t)q3 * 64 + lane];
            unsigned int u4 = Hwb[(size_t)q4 * 64 + lane];
            unsigned int u5 = Hwb[(size_t)q5 * 64 + lane];
            unsigned int u6 = Hwb[(size_t)q6 * 64 + lane];
            unsigned int u7 = Hwb[(size_t)q7 * 64 + lane];
            acc0 += w0 * __uint_as_float(u0 << 16);
            acc1 += w0 * __uint_as_float(u0 & 0xffff0000u);
            acc0 += w1 * __uint_as_float(u1 << 16);
            acc1 += w1 * __uint_as_float(u1 & 0xffff0000u);
            acc0 += w2 * __uint_as_float(u2 << 16);
            acc1 += w2 * __uint_as_float(u2 & 0xffff0000u);
            acc0 += w3 * __uint_as_float(u3 << 16);
            acc1 += w3 * __uint_as_float(u3 & 0xffff0000u);
            acc0 += w4 * __uint_as_float(u4 << 16);
            acc1 += w4 * __uint_as_float(u4 & 0xffff0000u);
            acc0 += w5 * __uint_as_float(u5 << 16);
            acc1 += w5 * __uint_as_float(u5 & 0xffff0000u);
            acc0 += w6 * __uint_as_float(u6 << 16);
            acc1 += w6 * __uint_as_float(u6 & 0xffff0000u);
            acc0 += w7 * __uint_as_float(u7 << 16);
            acc1 += w7 * __uint_as_float(u7 & 0xffff0000u);
        }
        for (; k + 4 <= cnt; k += 4) {
            int q0 = srcs[wave][k], q1 = srcs[wave][k + 1];
            int q2 = srcs[wave][k + 2], q3 = srcs[wave][k + 3];
            float w0 = wbuf[wave][k * 4 + h], w1 = wbuf[wave][(k + 1) * 4 + h];
            float w2 = wbuf[wave][(k + 2) * 4 + h], w3 = wbuf[wave][(k + 3) * 4 + h];
            unsigned int u0 = Hwb[(size_t)q0 * 64 + lane];
            unsigned int u1 = Hwb[(size_t)q1 * 64 + lane];
            unsigned int u2 = Hwb[(size_t)q2 * 64 + lane];
            unsigned int u3 = Hwb[(size_t)q3 * 64 + lane];
            acc0 += w0 * __uint_as_float(u0 << 16);
            acc1 += w0 * __uint_as_float(u0 & 0xffff0000u);
            acc0 += w1 * __uint_as_float(u1 << 16);
            acc1 += w1 * __uint_as_float(u1 & 0xffff0000u);
            acc0 += w2 * __uint_as_float(u2 << 16);
            acc1 += w2 * __uint_as_float(u2 & 0xffff0000u);
            acc0 += w3 * __uint_as_float(u3 << 16);
            acc1 += w3 * __uint_as_float(u3 & 0xffff0000u);
        }
        for (; k < cnt; ++k) {
            int q = srcs[wave][k];
            float w = wbuf[wave][k * 4 + h];
            unsigned int u = Hwb[(size_t)q * 64 + lane];
            acc0 += w * __uint_as_float(u << 16);
            acc1 += w * __uint_as_float(u & 0xffff0000u);
        }
    }

    for (int d = 1; d < 64; d <<= 1) {
        se0 += __shfl_xor(se0, d, 64);
        se1 += __shfl_xor(se1, d, 64);
        se2 += __shfl_xor(se2, d, 64);
        se3 += __shfl_xor(se3, d, 64);
    }
    float seh = (h == 0) ? se0 : (h == 1) ? se1 : (h == 2) ? se2 : se3;
    float inv = seh > 0.f ? 1.0f / seh : 0.f;
    acc0 *= inv;
    acc1 *= inv;
    acc0 = acc0 > 0.f ? acc0 : __expf(acc0) - 1.0f;
    acc1 = acc1 > 0.f ? acc1 : __expf(acc1) - 1.0f;

    int o = (2 * lane) & 31;
    float2v val = {acc0, acc1};
    *(float2v*)&out[(((size_t)h * nnodes + n) * 32) + o] = val;
}

extern "C" void kernel_launch(void* const* d_in, const int* in_sizes, int n_in,
                              void* d_out, int out_size, void* d_ws, size_t ws_size,
                              hipStream_t stream) {
    const float* Hin = (const float*)d_in[0];
    const int* ei_raw = (const int*)d_in[1];
    const float* W = (const float*)d_in[2];
    const float* Asrc = (const float*)d_in[3];
    const float* Atgt = (const float*)d_in[4];
    int N = in_sizes[0] / 128;
    int E = in_sizes[1] / 2;
    int NB = (N + 255) >> 8;        // node buckets (256 nodes each)
    int nblkE = (E + 16383) >> 14;  // edge blocks (16384 edges each)

    char* ws = (char*)d_ws;
    size_t p = 0;
    auto alloc = [&](size_t bytes) {
        void* r = ws + p;
        p = (p + bytes + 511) & ~(size_t)511;
        return r;
    };
    unsigned short* Hwb = (unsigned short*)alloc((size_t)N * 128 * 2);  // 25.6 MB
    float* s_src = (float*)alloc((size_t)N * 4 * 4);
    float* s_tgt = (float*)alloc((size_t)N * 4 * 4);
    int* offs = (int*)alloc((size_t)(N + 1) * 4);
    int* csr = (int*)alloc((size_t)E * 4);
    int* tgt32 = (int*)alloc((size_t)E * 4);
    uint2* pairs = (uint2*)alloc((size_t)E * 8);
    int* H = (int*)alloc((size_t)nblkE * NB * 4);
    int* base = (int*)alloc((size_t)(NB + 1) * 4);

    k_hist<<<dim3(nblkE), 256, 0, stream>>>(ei_raw, tgt32, H, E, N, NB);
    k_bscan<<<dim3(1), 1024, 0, stream>>>(H, base, offs, nblkE, NB, N, E);
    k_scat<<<dim3(nblkE), 256, 0, stream>>>(ei_raw, tgt32, H, pairs, E, N, NB);
    k_local<<<dim3(NB), 256, 0, stream>>>(pairs, base, offs, csr, N, NB);

    k_hw<<<dim3((N + 127) / 128), 256, 0, stream>>>(Hin, W, Asrc, Atgt, Hwb, s_src, s_tgt, N);

    k_aggr<<<dim3((N + 3) / 4), 256, 0, stream>>>(offs, csr, s_src, s_tgt,
                                                  (const unsigned int*)Hwb, (float*)d_out, N);
}